// Round 7
// baseline (609.664 us; speedup 1.0000x reference)
//
#include <hip/hip_runtime.h>

typedef unsigned short u16;
typedef unsigned int   u32;
typedef __attribute__((ext_vector_type(8)))  short bf16x8;
typedef __attribute__((ext_vector_type(4)))  float f32x4;
typedef __attribute__((ext_vector_type(16))) float f32x16;

// x: [4,64,256,256] f32; heads (cls,obj,box,pos,ins): od={81,2,4,64,128},
// out offsets {0,81,83,87,151}; out [4,279,256,256] f32.
constexpr int NPIX = 4 * 65536;

__device__ constexpr int OD_[5]   = {81, 2, 4, 64, 128};
__device__ constexpr int NFO_[5]  = {3, 1, 1, 2, 4};      // ceil(od/32)
__device__ constexpr int COFF_[5] = {0, 81, 83, 87, 151};
__device__ constexpr int FB_[5]   = {0, 36, 64, 92, 124}; // frag bases, 164 total

struct PW { const float* w[20]; };
struct PB { const float* x; float* out; const u16* wf; const float* b[20]; };

// f32 -> (hi bf16, lo bf16), truncation; hi+lo ~16 mantissa bits
__device__ __forceinline__ void split2(float v, short& hi, short& lo) {
    u32 bi = __builtin_bit_cast(u32, v);
    float lof = v - __builtin_bit_cast(float, bi & 0xffff0000u);
    hi = (short)(bi >> 16);
    lo = (short)(__builtin_bit_cast(u32, lof) >> 16);
}

// ---------------- pre-kernel: weights -> B-fragment order (hi/lo planes) ----
// frag*2048B = [hi 1024B][lo 1024B]; lane l elem j <-> B[k=ks*16+(l>>5)*8+j][col=nf*32+(l&31)]
// (identical (lane,j)->k map as the A-side below; k-permutation errors cancel)
__global__ __launch_bounds__(256) void prep_weights(PW wp, u16* wf) {
    int slot = blockIdx.x * 256 + threadIdx.x;
    if (slot >= 164 * 64) return;
    int frag = slot >> 6, lane = slot & 63;
    int fb = 0, seg = 0;
    for (int s = 0; s < 20; ++s) {
        int h = s >> 2, ly = s & 3;
        int cnt = (ly < 3) ? 8 : 4 * NFO_[h];
        if (frag < fb + cnt) { seg = s; break; }
        fb += cnt;
    }
    int h = seg >> 2, ly = seg & 3;
    int lf = frag - fb;
    int nf = lf >> 2, ks = lf & 3;
    int col  = nf * 32 + (lane & 31);
    int ksrc = ks * 16 + (lane >> 5) * 8;
    int rows = (ly < 3) ? 64 : OD_[h];
    const float* W = wp.w[seg];
    float wv[8];
    if (col < rows) {
        const float4* q = reinterpret_cast<const float4*>(W + col * 64 + ksrc);
        float4 a = q[0], c = q[1];
        wv[0]=a.x; wv[1]=a.y; wv[2]=a.z; wv[3]=a.w;
        wv[4]=c.x; wv[5]=c.y; wv[6]=c.z; wv[7]=c.w;
    } else {
#pragma unroll
        for (int j = 0; j < 8; ++j) wv[j] = 0.f;
    }
    bf16x8 vh, vl;
#pragma unroll
    for (int j = 0; j < 8; ++j) { short a, b; split2(wv[j], a, b); vh[j]=a; vl[j]=b; }
    u16* dst = wf + (size_t)frag * 1024 + lane * 8;
    *(bf16x8*)dst         = vh;
    *(bf16x8*)(dst + 512) = vl;
}

// H plane: [32 rows][64 ch] f32 (8 KiB/wave), XOR swizzle breaks the
// 256B-row-stride 32-way conflict on ds_read_b128 (residual ~4-way).
__device__ __forceinline__ u32 hswz(int row, int ch) {
    return (u32)((row << 8) + (ch << 2)) ^ (u32)((row & 7) << 4);
}

// load A-fragments (one ks slice) from H and split into hi/lo bf16
__device__ __forceinline__ void load_a(const char* H, int arow, int ks, int hb,
                                       bf16x8& ah, bf16x8& al) {
    u32 o0 = hswz(arow, ks * 16 + hb);
    f32x4 q0 = *(const f32x4*)(H + o0);
    f32x4 q1 = *(const f32x4*)(H + (o0 ^ 16));
    float qa[8] = {q0.x, q0.y, q0.z, q0.w, q1.x, q1.y, q1.z, q1.w};
#pragma unroll
    for (int j = 0; j < 8; ++j) { short a, b; split2(qa[j], a, b); ah[j]=a; al[j]=b; }
}

// one hidden ProjConv layer: D = A*W^T (3-term hi/lo), +bias, relu, optional
// +skip (exact f32 from H), write H. Wave-private LDS; DS in-order per wave;
// NO compiler fences -> scheduler may hoist next layer's global frag loads.
template<bool SKIP, bool FROM_LDS>
__device__ __forceinline__ void proj_layer(const bf16x8* Xh, const bf16x8* Xl,
                                           char* H, const u16* wfb,
                                           const float* bias, int l) {
    int hb = (l >> 5) * 8, arow = l & 31, hi4 = (l >> 5) * 4;
    f32x16 acc0, acc1;
#pragma unroll
    for (int i = 0; i < 16; ++i) { acc0[i] = 0.f; acc1[i] = 0.f; }
#pragma unroll
    for (int ks = 0; ks < 4; ++ks) {
        bf16x8 ah, al;
        if (FROM_LDS) load_a(H, arow, ks, hb, ah, al);
        else          { ah = Xh[ks]; al = Xl[ks]; }
        const u16* f0 = wfb + (size_t)ks * 1024;
        const u16* f1 = wfb + (size_t)(4 + ks) * 1024;
        bf16x8 b0h = *(const bf16x8*)f0, b0l = *(const bf16x8*)(f0 + 512);
        bf16x8 b1h = *(const bf16x8*)f1, b1l = *(const bf16x8*)(f1 + 512);
        acc0 = __builtin_amdgcn_mfma_f32_32x32x16_bf16(ah, b0h, acc0, 0, 0, 0);
        acc0 = __builtin_amdgcn_mfma_f32_32x32x16_bf16(ah, b0l, acc0, 0, 0, 0);
        acc0 = __builtin_amdgcn_mfma_f32_32x32x16_bf16(al, b0h, acc0, 0, 0, 0);
        acc1 = __builtin_amdgcn_mfma_f32_32x32x16_bf16(ah, b1h, acc1, 0, 0, 0);
        acc1 = __builtin_amdgcn_mfma_f32_32x32x16_bf16(ah, b1l, acc1, 0, 0, 0);
        acc1 = __builtin_amdgcn_mfma_f32_32x32x16_bf16(al, b1h, acc1, 0, 0, 0);
    }
    auto epi = [&](const f32x16& acc, int nf) {
        int ch = nf * 32 + (l & 31);
        float bv = bias[ch];
#pragma unroll
        for (int reg = 0; reg < 16; ++reg) {
            int row = (reg & 3) + 8 * (reg >> 2) + hi4;   // m74/m101 C-map
            u32 off = hswz(row, ch);
            float v = fmaxf(acc[reg] + bv, 0.f);
            if (SKIP) v += *(const float*)(H + off);
            *(float*)(H + off) = v;
        }
    };
    epi(acc0, 0);
    epi(acc1, 1);
}

// out layer: logits = W h + b, nontemporal float4 stores (output never re-read;
// avoids L2 write-allocate over-fetch seen in R5: FETCH 164 MB)
__device__ __forceinline__ void out_layer(const char* H, const u16* wfb,
                                          const float* bout, int od, int nfo,
                                          float* op_base, int l) {
    int hb = (l >> 5) * 8, arow = l & 31, hi4 = (l >> 5) * 4;
    bf16x8 Ah[4], Al[4];
#pragma unroll
    for (int ks = 0; ks < 4; ++ks) load_a(H, arow, ks, hb, Ah[ks], Al[ks]);
    for (int nf = 0; nf < nfo; ++nf) {
        f32x16 acc;
#pragma unroll
        for (int i = 0; i < 16; ++i) acc[i] = 0.f;
#pragma unroll
        for (int ks = 0; ks < 4; ++ks) {
            const u16* f = wfb + (size_t)(nf * 4 + ks) * 1024;
            bf16x8 bh = *(const bf16x8*)f, bl = *(const bf16x8*)(f + 512);
            acc = __builtin_amdgcn_mfma_f32_32x32x16_bf16(Ah[ks], bh, acc, 0, 0, 0);
            acc = __builtin_amdgcn_mfma_f32_32x32x16_bf16(Ah[ks], bl, acc, 0, 0, 0);
            acc = __builtin_amdgcn_mfma_f32_32x32x16_bf16(Al[ks], bh, acc, 0, 0, 0);
        }
        int col = nf * 32 + (l & 31);
        if (col < od) {
            float bv = bout[col];
            float* op = op_base + ((size_t)col << 16);
#pragma unroll
            for (int g = 0; g < 4; ++g) {
                int r0 = 8 * g + hi4;
                f32x4 st = {acc[4*g+0] + bv, acc[4*g+1] + bv,
                            acc[4*g+2] + bv, acc[4*g+3] + bv};
                __builtin_nontemporal_store(st, (f32x4*)(op + r0));
            }
        }
    }
}

// main: 4 waves/block, wave owns 32 pixels. X strip pre-split in registers
// (32 VGPR); H = 8 KiB f32 LDS/wave -> 32 KiB/block -> 4 blocks/CU.
__global__ __launch_bounds__(256, 4) void heads_main(PB p) {
    __shared__ char Hs[4][8192];
    int tid = threadIdx.x, w = tid >> 6, l = tid & 63;
    char* H = Hs[w];
    int p0 = blockIdx.x * 128 + w * 32;
    int b = p0 >> 16, hw0 = p0 & 65535;
    int hb = (l >> 5) * 8;
    const float* xb = p.x + ((size_t)(b * 64) << 16) + hw0 + (l & 31);

    bf16x8 Xh[4], Xl[4];
#pragma unroll
    for (int ks = 0; ks < 4; ++ks)
#pragma unroll
        for (int j = 0; j < 8; ++j) {
            int ch = ks * 16 + hb + j;
            float v = xb[(size_t)ch << 16];
            short a, c; split2(v, a, c);
            Xh[ks][j] = a; Xl[ks][j] = c;
        }

    const u16* wfl = p.wf + l * 8;
    for (int h = 0; h < 5; ++h) {
        const u16* wfb = wfl + (size_t)FB_[h] * 1024;
        proj_layer<false, false>(Xh, Xl, H, wfb,              p.b[4*h+0], l);
        proj_layer<true,  true >(Xh, Xl, H, wfb +  8 * 1024,  p.b[4*h+1], l);
        proj_layer<true,  true >(Xh, Xl, H, wfb + 16 * 1024,  p.b[4*h+2], l);
        float* op = p.out + ((size_t)(b * 279 + COFF_[h]) << 16) + hw0;
        out_layer(H, wfb + 24 * 1024, p.b[4*h+3], OD_[h], NFO_[h], op, l);
    }
}

extern "C" void kernel_launch(void* const* d_in, const int* in_sizes, int n_in,
                              void* d_out, int out_size, void* d_ws, size_t ws_size,
                              hipStream_t stream)
{
    auto A = [&](int i) { return (const float*)d_in[i]; };
    PW wp; PB pb;
    for (int h = 0; h < 5; ++h) {
        wp.w[4*h+0] = A(1 + 6*h + 0);           // Win
        wp.w[4*h+1] = A(1 + 6*h + 2);           // Wh[0]
        wp.w[4*h+2] = A(1 + 6*h + 2) + 4096;    // Wh[1]
        wp.w[4*h+3] = A(1 + 6*h + 4);           // Wout
        pb.b[4*h+0] = A(1 + 6*h + 1);           // bin
        pb.b[4*h+1] = A(1 + 6*h + 3);           // bh[0]
        pb.b[4*h+2] = A(1 + 6*h + 3) + 64;      // bh[1]
        pb.b[4*h+3] = A(1 + 6*h + 5);           // bout
    }
    u16* wf = (u16*)d_ws;                       // 164*2048 = 328 KiB
    pb.x = (const float*)d_in[0];
    pb.out = (float*)d_out;
    pb.wf = wf;

    prep_weights<<<41, 256, 0, stream>>>(wp, wf);
    heads_main<<<NPIX / 128, 256, 0, stream>>>(pb);
}

// Round 10
// 531.118 us; speedup vs baseline: 1.1479x; 1.1479x over previous
//
#include <hip/hip_runtime.h>

typedef unsigned short u16;
typedef unsigned int   u32;
typedef __attribute__((ext_vector_type(8)))  short bf16x8;
typedef __attribute__((ext_vector_type(4)))  float f32x4;
typedef __attribute__((ext_vector_type(16))) float f32x16;

// x: [4,64,256,256] f32; heads (cls,obj,box,pos,ins): od={81,2,4,64,128},
// out offsets {0,81,83,87,151}; out [4,279,256,256] f32.
constexpr int NPIX = 4 * 65536;

__device__ constexpr int OD_[5]   = {81, 2, 4, 64, 128};
__device__ constexpr int NFO_[5]  = {3, 1, 1, 2, 4};      // ceil(od/32)
__device__ constexpr int FB_[5]   = {0, 36, 64, 92, 124}; // frag bases, 164 total

struct PW { const float* w[20]; };
struct PB { const float* x; float* out; const u16* wf; const float* b[20]; };

// f32 -> (hi bf16, lo bf16), truncation; hi+lo ~16 mantissa bits
__device__ __forceinline__ void split2(float v, short& hi, short& lo) {
    u32 bi = __builtin_bit_cast(u32, v);
    float lof = v - __builtin_bit_cast(float, bi & 0xffff0000u);
    hi = (short)(bi >> 16);
    lo = (short)(__builtin_bit_cast(u32, lof) >> 16);
}

// ---------------- pre-kernel: weights -> B-fragment order (hi/lo planes) ----
// frag*2048B = [hi 1024B][lo 1024B]; lane l elem j <-> B[k=ks*16+(l>>5)*8+j][col=nf*32+(l&31)]
// (identical (lane,j)->k map as the A-side below; k-permutation errors cancel)
__global__ __launch_bounds__(256) void prep_weights(PW wp, u16* wf) {
    int slot = blockIdx.x * 256 + threadIdx.x;
    if (slot >= 164 * 64) return;
    int frag = slot >> 6, lane = slot & 63;
    int fb = 0, seg = 0;
    for (int s = 0; s < 20; ++s) {
        int h = s >> 2, ly = s & 3;
        int cnt = (ly < 3) ? 8 : 4 * NFO_[h];
        if (frag < fb + cnt) { seg = s; break; }
        fb += cnt;
    }
    int h = seg >> 2, ly = seg & 3;
    int lf = frag - fb;
    int nf = lf >> 2, ks = lf & 3;
    int col  = nf * 32 + (lane & 31);
    int ksrc = ks * 16 + (lane >> 5) * 8;
    int rows = (ly < 3) ? 64 : OD_[h];
    const float* W = wp.w[seg];
    float wv[8];
    if (col < rows) {
        const float4* q = reinterpret_cast<const float4*>(W + col * 64 + ksrc);
        float4 a = q[0], c = q[1];
        wv[0]=a.x; wv[1]=a.y; wv[2]=a.z; wv[3]=a.w;
        wv[4]=c.x; wv[5]=c.y; wv[6]=c.z; wv[7]=c.w;
    } else {
#pragma unroll
        for (int j = 0; j < 8; ++j) wv[j] = 0.f;
    }
    bf16x8 vh, vl;
#pragma unroll
    for (int j = 0; j < 8; ++j) { short a, b; split2(wv[j], a, b); vh[j]=a; vl[j]=b; }
    u16* dst = wf + (size_t)frag * 1024 + lane * 8;
    *(bf16x8*)dst         = vh;
    *(bf16x8*)(dst + 512) = vl;
}

// H plane: [32 rows][64 ch] f32 (8 KiB/wave), XOR swizzle breaks the
// 256B-row-stride 32-way conflict on ds_read_b128 (residual ~4-way).
__device__ __forceinline__ u32 hswz(int row, int ch) {
    return (u32)((row << 8) + (ch << 2)) ^ (u32)((row & 7) << 4);
}

// load A-fragments (one ks slice) from H and split into hi/lo bf16
__device__ __forceinline__ void load_a(const char* H, int arow, int ks, int hb,
                                       bf16x8& ah, bf16x8& al) {
    u32 o0 = hswz(arow, ks * 16 + hb);
    f32x4 q0 = *(const f32x4*)(H + o0);
    f32x4 q1 = *(const f32x4*)(H + (o0 ^ 16));
    float qa[8] = {q0.x, q0.y, q0.z, q0.w, q1.x, q1.y, q1.z, q1.w};
#pragma unroll
    for (int j = 0; j < 8; ++j) { short a, b; split2(qa[j], a, b); ah[j]=a; al[j]=b; }
}

#define MFMA3(ACC, AH, AL, BH, BL)                                              \
    ACC = __builtin_amdgcn_mfma_f32_32x32x16_bf16(AH, BH, ACC, 0, 0, 0);        \
    ACC = __builtin_amdgcn_mfma_f32_32x32x16_bf16(AH, BL, ACC, 0, 0, 0);        \
    ACC = __builtin_amdgcn_mfma_f32_32x32x16_bf16(AL, BH, ACC, 0, 0, 0);

// One head, fully static. Register-rotation prefetch: Ph/Pl[8] hold frags
// f..f+7 of this head's stream; consuming frag f issues the load of f+8 into
// the same slot. Slot reuse forces load-issue one full layer ahead of use ->
// L2 latency hidden by construction.
template<int NFO>
__device__ __forceinline__ void head_body(const bf16x8* Xh, const bf16x8* Xl,
                                          char* H, const u16* wfb,
                                          const float* b0, const float* b1,
                                          const float* b2, const float* bout,
                                          int od, float* op_base, int l) {
    constexpr int NFRAG = 24 + 4 * NFO;
    int hb = (l >> 5) * 8, arow = l & 31, hi4 = (l >> 5) * 4;

    bf16x8 Ph[8], Pl[8];
#pragma unroll
    for (int f = 0; f < 8; ++f) {           // prime: L0's 8 frags
        const u16* fp = wfb + (size_t)f * 1024;
        Ph[f] = *(const bf16x8*)fp;
        Pl[f] = *(const bf16x8*)(fp + 512);
    }

    // ---- hidden layers ----
#pragma unroll
    for (int ly = 0; ly < 3; ++ly) {
        bf16x8 Ah[4], Al[4];
#pragma unroll
        for (int ks = 0; ks < 4; ++ks) {
            if (ly == 0) { Ah[ks] = Xh[ks]; Al[ks] = Xl[ks]; }
            else         load_a(H, arow, ks, hb, Ah[ks], Al[ks]);
        }
        const float* bias = (ly == 0) ? b0 : ((ly == 1) ? b1 : b2);
        f32x16 acc0, acc1;
#pragma unroll
        for (int i = 0; i < 16; ++i) { acc0[i] = 0.f; acc1[i] = 0.f; }
#pragma unroll
        for (int nf = 0; nf < 2; ++nf)
#pragma unroll
            for (int ks = 0; ks < 4; ++ks) {
                int fi = ly * 8 + nf * 4 + ks;   // stream index (static)
                int c  = fi & 7;
                if (nf == 0) { MFMA3(acc0, Ah[ks], Al[ks], Ph[c], Pl[c]); }
                else         { MFMA3(acc1, Ah[ks], Al[ks], Ph[c], Pl[c]); }
                int nx = fi + 8;                 // prefetch next layer's frag
                if (nx < NFRAG) {
                    const u16* fp = wfb + (size_t)nx * 1024;
                    Ph[c] = *(const bf16x8*)fp;
                    Pl[c] = *(const bf16x8*)(fp + 512);
                }
            }
        // epilogue: +bias, relu, +skip (ly>0), write H
#pragma unroll
        for (int nf = 0; nf < 2; ++nf) {
            int ch = nf * 32 + (l & 31);
            float bv = bias[ch];
#pragma unroll
            for (int reg = 0; reg < 16; ++reg) {
                int row = (reg & 3) + 8 * (reg >> 2) + hi4;  // m74/m101 C-map
                u32 off = hswz(row, ch);
                float a = (nf == 0) ? acc0[reg] : acc1[reg];
                float v = fmaxf(a + bv, 0.f);
                if (ly > 0) v += *(const float*)(H + off);
                *(float*)(H + off) = v;
            }
        }
    }

    // ---- out layer ----
    bf16x8 Ah[4], Al[4];
#pragma unroll
    for (int ks = 0; ks < 4; ++ks) load_a(H, arow, ks, hb, Ah[ks], Al[ks]);
#pragma unroll
    for (int nf = 0; nf < NFO; ++nf) {
        f32x16 acc;
#pragma unroll
        for (int i = 0; i < 16; ++i) acc[i] = 0.f;
#pragma unroll
        for (int ks = 0; ks < 4; ++ks) {
            int fi = 24 + nf * 4 + ks;
            int c  = fi & 7;
            MFMA3(acc, Ah[ks], Al[ks], Ph[c], Pl[c]);
            int nx = fi + 8;
            if (nx < NFRAG) {
                const u16* fp = wfb + (size_t)nx * 1024;
                Ph[c] = *(const bf16x8*)fp;
                Pl[c] = *(const bf16x8*)(fp + 512);
            }
        }
        int col = nf * 32 + (l & 31);
        if (col < od) {
            float bv = bout[col];
            float* op = op_base + ((size_t)col << 16);
#pragma unroll
            for (int g = 0; g < 4; ++g) {
                int r0 = 8 * g + hi4;
                f32x4 st = {acc[4*g+0] + bv, acc[4*g+1] + bv,
                            acc[4*g+2] + bv, acc[4*g+3] + bv};
                *(f32x4*)(op + r0) = st;        // plain stores (nt regressed, R7)
            }
        }
    }
}

// main: 4 waves/block, wave owns 32 pixels. X pre-split in regs (32 VGPR);
// H = 8 KiB f32 LDS/wave -> 32 KiB/block. (256,3): VGPR cap 170 for the
// ~158-reg prefetch pipeline; 12 waves/CU.
__global__ __launch_bounds__(256, 3) void heads_main(PB p) {
    __shared__ char Hs[4][8192];
    int tid = threadIdx.x, w = tid >> 6, l = tid & 63;
    char* H = Hs[w];
    int p0 = blockIdx.x * 128 + w * 32;
    int b = p0 >> 16, hw0 = p0 & 65535;
    int hb = (l >> 5) * 8;
    const float* xb = p.x + ((size_t)(b * 64) << 16) + hw0 + (l & 31);

    bf16x8 Xh[4], Xl[4];
#pragma unroll
    for (int ks = 0; ks < 4; ++ks)
#pragma unroll
        for (int j = 0; j < 8; ++j) {
            int ch = ks * 16 + hb + j;
            float v = xb[(size_t)ch << 16];
            short a, c; split2(v, a, c);
            Xh[ks][j] = a; Xl[ks][j] = c;
        }

    const u16* wfl = p.wf + l * 8;
    size_t ob = ((size_t)b * 279) << 16;
    head_body<3>(Xh, Xl, H, wfl + (size_t)FB_[0] * 1024, p.b[0],  p.b[1],  p.b[2],  p.b[3],   81, p.out + ob + (((size_t)  0) << 16) + hw0, l);
    head_body<1>(Xh, Xl, H, wfl + (size_t)FB_[1] * 1024, p.b[4],  p.b[5],  p.b[6],  p.b[7],    2, p.out + ob + (((size_t) 81) << 16) + hw0, l);
    head_body<1>(Xh, Xl, H, wfl + (size_t)FB_[2] * 1024, p.b[8],  p.b[9],  p.b[10], p.b[11],   4, p.out + ob + (((size_t) 83) << 16) + hw0, l);
    head_body<2>(Xh, Xl, H, wfl + (size_t)FB_[3] * 1024, p.b[12], p.b[13], p.b[14], p.b[15],  64, p.out + ob + (((size_t) 87) << 16) + hw0, l);
    head_body<4>(Xh, Xl, H, wfl + (size_t)FB_[4] * 1024, p.b[16], p.b[17], p.b[18], p.b[19], 128, p.out + ob + (((size_t)151) << 16) + hw0, l);
}

extern "C" void kernel_launch(void* const* d_in, const int* in_sizes, int n_in,
                              void* d_out, int out_size, void* d_ws, size_t ws_size,
                              hipStream_t stream)
{
    auto A = [&](int i) { return (const float*)d_in[i]; };
    PW wp; PB pb;
    for (int h = 0; h < 5; ++h) {
        wp.w[4*h+0] = A(1 + 6*h + 0);           // Win
        wp.w[4*h+1] = A(1 + 6*h + 2);           // Wh[0]
        wp.w[4*h+2] = A(1 + 6*h + 2) + 4096;    // Wh[1]
        wp.w[4*h+3] = A(1 + 6*h + 4);           // Wout
        pb.b[4*h+0] = A(1 + 6*h + 1);           // bin
        pb.b[4*h+1] = A(1 + 6*h + 3);           // bh[0]
        pb.b[4*h+2] = A(1 + 6*h + 3) + 64;      // bh[1]
        pb.b[4*h+3] = A(1 + 6*h + 5);           // bout
    }
    u16* wf = (u16*)d_ws;                       // 164*2048 = 328 KiB
    pb.x = (const float*)d_in[0];
    pb.out = (float*)d_out;
    pb.wf = wf;

    prep_weights<<<41, 256, 0, stream>>>(wp, wf);
    heads_main<<<NPIX / 128, 256, 0, stream>>>(pb);
}